// Round 4
// baseline (309.715 us; speedup 1.0000x reference)
//
#include <hip/hip_runtime.h>
#include <math.h>

typedef short bf16x8 __attribute__((ext_vector_type(8)));
typedef float f32x4 __attribute__((ext_vector_type(4)));

#define BDIM 256
constexpr int B_ = 2, H_ = 16, L_ = 1024, D_ = 64, LMAX_ = 2048;
constexpr int BH_ = B_ * H_;
constexpr float PI_F = 3.14159265358979323846f;

// ws float offsets
constexpr int WS_A   = 0;        // fp32 a[4][1024]
constexpr int WS_ECR = 4096;     // fp32 [1024]
constexpr int WS_ECI = 5120;     // fp32 [1024]
constexpr int WS_SVP = 6144;     // fp32 [2][32][4][64]  SumV partials
constexpr int WS_AMB = 22528;    // u16 [16][1024] (a/8 bf16, rows 4-15 zero)
constexpr int WS_AM2 = 30720;    // u16 [16][1024] ((a/8)^2 bf16, rows 4-15 zero)
constexpr int WS_KBR = 40960;    // u16 [32][1024][64] K real bf16
constexpr int WS_KBI = WS_KBR + 1048576;
constexpr int WS_VTR = WS_KBI + 1048576;  // u16 [32][64][1024] V^T real bf16
constexpr int WS_VTI = WS_VTR + 1048576;

__device__ __forceinline__ unsigned short f2b(float x) {
    union { float f; unsigned u; } v; v.f = x;
    return (unsigned short)((v.u + 0x8000u) >> 16);
}
__device__ __forceinline__ unsigned pk2(float a, float b) {
    return (unsigned)f2b(a) | ((unsigned)f2b(b) << 16);
}

#define MFMA(a, b, c) __builtin_amdgcn_mfma_f32_16x16x32_bf16((a), (b), (c), 0, 0, 0)

// 1568 uniform blocks. invn = host-computed 1/sqrt(norm) per scale (closed form).
__global__ void prep_kernel(const float* __restrict__ Kr, const float* __restrict__ Ki,
                            const float* __restrict__ Vr, const float* __restrict__ Vi,
                            float* __restrict__ ws, float4 invn) {
    const int tid = threadIdx.x;
    const int blk = blockIdx.x;
    unsigned short* KbR = (unsigned short*)(ws + WS_KBR);
    unsigned short* KbI = (unsigned short*)(ws + WS_KBI);
    unsigned short* VtR = (unsigned short*)(ws + WS_VTR);
    unsigned short* VtI = (unsigned short*)(ws + WS_VTI);

    if (blk < 256) {
        // K -> bf16 flat copy. 128 blocks per component, 16384 elems each.
        const float* src = (blk < 128) ? Kr : Ki;
        unsigned short* dst = (blk < 128) ? KbR : KbI;
        size_t b0 = (size_t)(blk & 127) * 16384;
#pragma unroll
        for (int i = 0; i < 8; ++i) {
            size_t e = b0 + (size_t)(i * 256 + tid) * 8;
            float4 x = *(const float4*)(src + e);
            float4 y = *(const float4*)(src + e + 4);
            *(uint4*)(dst + e) =
                make_uint4(pk2(x.x, x.y), pk2(x.z, x.w), pk2(y.x, y.y), pk2(y.z, y.w));
        }
    } else if (blk < 1280) {
        // V -> V^T bf16 [bh][d][m]; one 64x64 tile, one component per block
        __shared__ unsigned short sT[64 * 68];
        int vb = blk - 256;
        int comp = vb & 1, rest = vb >> 1;
        int bh = rest >> 4, mt = rest & 15, m0 = mt * 64;
        const float* src = (comp ? Vi : Vr) + (size_t)bh * 65536;
        unsigned short* dstA = comp ? VtI : VtR;
#pragma unroll
        for (int i = 0; i < 4; ++i) {
            int e = i * 256 + tid;
            int m = e >> 4, d4 = (e & 15) * 4;
            float4 x = *(const float4*)(src + (size_t)(m0 + m) * 64 + d4);
            *(uint2*)&sT[m * 68 + d4] = make_uint2(pk2(x.x, x.y), pk2(x.z, x.w));
        }
        __syncthreads();
        {
            int d = tid >> 2, ms = (tid & 3) * 16;
            unsigned short v[16];
#pragma unroll
            for (int k = 0; k < 16; ++k) v[k] = sT[(ms + k) * 68 + d];
            uint4 p0 = make_uint4((unsigned)v[0] | ((unsigned)v[1] << 16),
                                  (unsigned)v[2] | ((unsigned)v[3] << 16),
                                  (unsigned)v[4] | ((unsigned)v[5] << 16),
                                  (unsigned)v[6] | ((unsigned)v[7] << 16));
            uint4 p1 = make_uint4((unsigned)v[8] | ((unsigned)v[9] << 16),
                                  (unsigned)v[10] | ((unsigned)v[11] << 16),
                                  (unsigned)v[12] | ((unsigned)v[13] << 16),
                                  (unsigned)v[14] | ((unsigned)v[15] << 16));
            unsigned short* dst = dstA + (size_t)bh * 65536 + (size_t)d * 1024 + m0 + ms;
            *(uint4*)dst = p0;
            *(uint4*)(dst + 8) = p1;
        }
    } else if (blk < 1536) {
        // SumV partials: [comp][bh][chunk(4)][d]
        int idx = blk - 1280;
        int comp = idx & 1, bh = (idx >> 1) & 31, chunk = idx >> 6;
        const float* src = (comp ? Vi : Vr) + (size_t)bh * 65536;
        int d = tid & 63, grp = tid >> 6;
        float s = 0.0f;
        int mb = chunk * 256 + grp * 64;
        for (int m = mb; m < mb + 64; ++m) s += src[m * 64 + d];
        __shared__ float red[4][64];
        red[grp][d] = s;
        __syncthreads();
        if (grp == 0)
            ws[WS_SVP + comp * 8192 + bh * 256 + chunk * 64 + d] =
                red[0][d] + red[1][d] + red[2][d] + red[3][d];
    } else if (blk < 1552) {
        // a-tables (norm from host): 4 scales x 4 parts
        int t = blk - 1536;
        int s = t >> 2;
        int l = (t & 3) * 256 + tid;
        const float freqs[4] = {1.0f, 0.5f, 0.25f, 0.1f};
        float inv = (s == 0) ? invn.x : (s == 1) ? invn.y : (s == 2) ? invn.z : invn.w;
        float step = 2.0f * PI_F * freqs[s] / (float)(LMAX_ - 1);
        float tt = step * (float)l;
        float m2 = 3.0f + 2.0f * cosf(tt) + 2.0f * cosf(0.5f * tt) + 2.0f * cosf(1.5f * tt);
        float av = sqrtf(fmaxf(m2, 0.0f)) * inv;
        ws[WS_A + s * 1024 + l] = av;
        float a8 = av * 0.125f;
        ((unsigned short*)(ws + WS_AMB))[s * 1024 + l] = f2b(a8);
        ((unsigned short*)(ws + WS_AM2))[s * 1024 + l] = f2b(a8 * a8);
    } else if (blk < 1556) {
        // expert tables
        int l = (blk - 1552) * 256 + tid;
        float step = 2.0f * PI_F / (float)(LMAX_ - 1);
        const float c = rsqrtf((float)LMAX_) / (sqrtf(3.0f) * sqrtf(8.0f));
        float t = step * (float)l;
        float sr = 0.0f, si = 0.0f;
#pragma unroll
        for (int i = 0; i < 8; ++i) {
            float fb = 0.1f * (float)i;
            float t1 = (0.3f + fb) * t, t2 = (0.2f + fb) * t, t3 = (0.1f + fb) * t;
            sr += cosf(t1) + cosf(t2) + cosf(t3);
            si += sinf(t1) + sinf(t2) + sinf(t3);
        }
        ws[WS_ECR + l] = sr * c;
        ws[WS_ECI + l] = si * c;
    } else {
        // zero amb/am2 rows 4..15
        int row = 4 + (blk - 1556);
        unsigned* a1 = (unsigned*)(ws + WS_AMB);
        unsigned* a2 = (unsigned*)(ws + WS_AM2);
        a1[row * 512 + tid] = 0; a1[row * 512 + 256 + tid] = 0;
        a2[row * 512 + tid] = 0; a2[row * 512 + 256 + tid] = 0;
    }
}

// read a b128 fragment from swizzled sE [64 rows][72], logical granule g
__device__ __forceinline__ bf16x8 ldfragE(const unsigned short* b, int row, int g) {
    return *(const bf16x8*)&b[row * 72 + ((g ^ (row & 7)) << 3)];
}

// Zero-__syncthreads attention kernel: all MFMA operands direct from global
// (bf16 K / V^T / tables in ws, L2/L3 resident); LDS only for same-wave
// score round-trips (sE) and same-wave den exchange (sDen).
__launch_bounds__(BDIM, 2)
__global__ void attn3_kernel(const float* __restrict__ Qr, const float* __restrict__ Qi,
                             const float* __restrict__ ws, float* __restrict__ out) {
    __shared__ unsigned short sE[64 * 72];
    __shared__ float sDen[4][64];

    const int tid = threadIdx.x;
    const int lane = tid & 63;
    const int w = tid >> 6;
    const int lo16 = lane & 15;
    const int quad = lane >> 4;
    const int blk = blockIdx.x;
    // XCD-clustered mapping: XCD x serves bh 4x..4x+3 (K/V^T working set ~3MB/XCD-L2)
    const int bh = (blk & 7) * 4 + (blk >> 7);
    const int qt = (blk >> 3) & 15;
    const int l0 = qt * 64;
    const size_t base = (size_t)bh * (L_ * D_);

    const float* aT = ws + WS_A;
    const unsigned short* ambU = (const unsigned short*)(ws + WS_AMB);
    const unsigned short* am2U = (const unsigned short*)(ws + WS_AM2);
    const unsigned short* gKr = (const unsigned short*)(ws + WS_KBR) + (size_t)bh * 65536;
    const unsigned short* gKi = (const unsigned short*)(ws + WS_KBI) + (size_t)bh * 65536;
    const unsigned short* gVr = (const unsigned short*)(ws + WS_VTR) + (size_t)bh * 65536;
    const unsigned short* gVi = (const unsigned short*)(ws + WS_VTI) + (size_t)bh * 65536;

    // ---- Q fragments straight from global fp32 (once) ----
    const int ql = l0 + w * 16 + lo16;
    bf16x8 fQr0, fQr1, fQi0, fQi1, fnQi0, fnQi1;
    {
        const float* qr = Qr + base + (size_t)ql * 64;
        const float* qi = Qi + base + (size_t)ql * 64;
        float4 a0 = *(const float4*)(qr + quad * 8);
        float4 a1 = *(const float4*)(qr + quad * 8 + 4);
        float4 b0 = *(const float4*)(qr + 32 + quad * 8);
        float4 b1 = *(const float4*)(qr + 32 + quad * 8 + 4);
        *(uint4*)&fQr0 = make_uint4(pk2(a0.x,a0.y), pk2(a0.z,a0.w), pk2(a1.x,a1.y), pk2(a1.z,a1.w));
        *(uint4*)&fQr1 = make_uint4(pk2(b0.x,b0.y), pk2(b0.z,b0.w), pk2(b1.x,b1.y), pk2(b1.z,b1.w));
        a0 = *(const float4*)(qi + quad * 8);
        a1 = *(const float4*)(qi + quad * 8 + 4);
        b0 = *(const float4*)(qi + 32 + quad * 8);
        b1 = *(const float4*)(qi + 32 + quad * 8 + 4);
        *(uint4*)&fQi0 = make_uint4(pk2(a0.x,a0.y), pk2(a0.z,a0.w), pk2(a1.x,a1.y), pk2(a1.z,a1.w));
        *(uint4*)&fQi1 = make_uint4(pk2(b0.x,b0.y), pk2(b0.z,b0.w), pk2(b1.x,b1.y), pk2(b1.z,b1.w));
        uint4 t0 = *(uint4*)&fQi0, t1 = *(uint4*)&fQi1;
        t0.x ^= 0x80008000u; t0.y ^= 0x80008000u; t0.z ^= 0x80008000u; t0.w ^= 0x80008000u;
        t1.x ^= 0x80008000u; t1.y ^= 0x80008000u; t1.z ^= 0x80008000u; t1.w ^= 0x80008000u;
        *(uint4*)&fnQi0 = t0; *(uint4*)&fnQi1 = t1;
    }
    unsigned short* sEw = sE;  // rows w*16..w*16+15 are this wave's slab

    // ---- sweep 0: |S0| -> MFMA matvec -> denominators ----
    f32x4 accM1 = (f32x4){0.f, 0.f, 0.f, 0.f};
    for (int mt = 0; mt < 16; ++mt) {
        const int m0 = mt * 64;
#pragma unroll
        for (int ct = 0; ct < 4; ++ct) {
            const int mrow = m0 + ct * 16 + lo16;
            bf16x8 kr0 = *(const bf16x8*)&gKr[(size_t)mrow * 64 + quad * 8];
            bf16x8 kr1 = *(const bf16x8*)&gKr[(size_t)mrow * 64 + 32 + quad * 8];
            bf16x8 ki0 = *(const bf16x8*)&gKi[(size_t)mrow * 64 + quad * 8];
            bf16x8 ki1 = *(const bf16x8*)&gKi[(size_t)mrow * 64 + 32 + quad * 8];
            f32x4 aR = (f32x4){0.f, 0.f, 0.f, 0.f};
            f32x4 aI = (f32x4){0.f, 0.f, 0.f, 0.f};
            aR = MFMA(kr0, fQr0, aR);  aR = MFMA(kr1, fQr1, aR);   // S^T = K·Q^T
            aR = MFMA(ki0, fnQi0, aR); aR = MFMA(ki1, fnQi1, aR);
            aI = MFMA(ki0, fQr0, aI);  aI = MFMA(ki1, fQr1, aI);
            aI = MFMA(kr0, fQi0, aI);  aI = MFMA(kr1, fQi1, aI);
            float mg0 = sqrtf(fmaf(aR[0], aR[0], aI[0] * aI[0]));
            float mg1 = sqrtf(fmaf(aR[1], aR[1], aI[1] * aI[1]));
            float mg2 = sqrtf(fmaf(aR[2], aR[2], aI[2] * aI[2]));
            float mg3 = sqrtf(fmaf(aR[3], aR[3], aI[3] * aI[3]));
            // transposed C/D: regs are 4 consecutive m for column l -> one b64
            int l = w * 16 + lo16;
            int phys = (ct * 2 + (quad >> 1)) ^ (l & 7);
            *(uint2*)&sE[l * 72 + phys * 8 + (quad & 1) * 4] =
                make_uint2(pk2(mg0, mg1), pk2(mg2, mg3));
        }
        // M1[l][s] += mag @ amb  (A rows: own slab, same-wave LDS dep)
        bf16x8 mf0 = ldfragE(sEw, w * 16 + lo16, quad);
        bf16x8 mf1 = ldfragE(sEw, w * 16 + lo16, quad + 4);
        bf16x8 b0 = *(const bf16x8*)&ambU[lo16 * 1024 + m0 + quad * 8];
        bf16x8 b1 = *(const bf16x8*)&ambU[lo16 * 1024 + m0 + 32 + quad * 8];
        accM1 = MFMA(mf0, b0, accM1);
        accM1 = MFMA(mf1, b1, accM1);
    }
    // den_s[l] = 1024 + al_s[l]*M1[l,s]; exchange within wave via sDen
    if (lo16 < 4) {
#pragma unroll
        for (int reg = 0; reg < 4; ++reg) {
            int r = w * 16 + quad * 4 + reg;
            float alv = aT[lo16 * 1024 + l0 + r];
            sDen[lo16][r] = 1.0f / (1024.0f + alv * accM1[reg]);
        }
    }
    bf16x8 uf1 = (bf16x8){0, 0, 0, 0, 0, 0, 0, 0};
    bf16x8 uf2 = (bf16x8){0, 0, 0, 0, 0, 0, 0, 0};
    {
        float invq = sDen[quad][w * 16 + lo16];   // same-wave LDS (in-order DS pipe)
        float alq = aT[quad * 1024 + l0 + w * 16 + lo16];
        uf1[0] = (short)f2b(invq * alq);
        uf2[0] = (short)f2b(0.5f * invq * alq * alq);
    }

    // ---- sweep 1: P' (rank-4 via MFMA) + PV ----
    f32x4 aOutR[4], aOutI[4];
#pragma unroll
    for (int dt = 0; dt < 4; ++dt) {
        aOutR[dt] = (f32x4){0.f, 0.f, 0.f, 0.f};
        aOutI[dt] = (f32x4){0.f, 0.f, 0.f, 0.f};
    }
    for (int mt = 0; mt < 16; ++mt) {
        const int m0 = mt * 64;
#pragma unroll
        for (int ct = 0; ct < 4; ++ct) {
            const int mrow = m0 + ct * 16 + lo16;
            bf16x8 kr0 = *(const bf16x8*)&gKr[(size_t)mrow * 64 + quad * 8];
            bf16x8 kr1 = *(const bf16x8*)&gKr[(size_t)mrow * 64 + 32 + quad * 8];
            bf16x8 ki0 = *(const bf16x8*)&gKi[(size_t)mrow * 64 + quad * 8];
            bf16x8 ki1 = *(const bf16x8*)&gKi[(size_t)mrow * 64 + 32 + quad * 8];
            f32x4 aR = (f32x4){0.f, 0.f, 0.f, 0.f};
            f32x4 aI = (f32x4){0.f, 0.f, 0.f, 0.f};
            aR = MFMA(kr0, fQr0, aR);  aR = MFMA(kr1, fQr1, aR);
            aR = MFMA(ki0, fnQi0, aR); aR = MFMA(ki1, fnQi1, aR);
            aI = MFMA(ki0, fQr0, aI);  aI = MFMA(ki1, fQr1, aI);
            aI = MFMA(kr0, fQi0, aI);  aI = MFMA(kr1, fQi1, aI);
            // A1^T/A2^T rank-4 tiles (operands swapped vs untransposed version)
            bf16x8 bf1 = (bf16x8){0, 0, 0, 0, 0, 0, 0, 0};
            bf16x8 bf2 = (bf16x8){0, 0, 0, 0, 0, 0, 0, 0};
            bf1[0] = (short)ambU[quad * 1024 + m0 + ct * 16 + lo16];
            bf2[0] = (short)am2U[quad * 1024 + m0 + ct * 16 + lo16];
            f32x4 z = (f32x4){0.f, 0.f, 0.f, 0.f};
            f32x4 a1 = MFMA(bf1, uf1, z);
            f32x4 a2 = MFMA(bf2, uf2, z);
            float p0, p1, p2, p3;
            {
                float msq = fmaf(aR[0], aR[0], aI[0] * aI[0]);
                p0 = fmaf(sqrtf(msq), a1[0], msq * a2[0]);
                msq = fmaf(aR[1], aR[1], aI[1] * aI[1]);
                p1 = fmaf(sqrtf(msq), a1[1], msq * a2[1]);
                msq = fmaf(aR[2], aR[2], aI[2] * aI[2]);
                p2 = fmaf(sqrtf(msq), a1[2], msq * a2[2]);
                msq = fmaf(aR[3], aR[3], aI[3] * aI[3]);
                p3 = fmaf(sqrtf(msq), a1[3], msq * a2[3]);
            }
            int l = w * 16 + lo16;
            int phys = (ct * 2 + (quad >> 1)) ^ (l & 7);
            *(uint2*)&sE[l * 72 + phys * 8 + (quad & 1) * 4] =
                make_uint2(pk2(p0, p1), pk2(p2, p3));
        }
        // PV: out += P' @ V   (A: own slab; B: V^T fragments from global)
        bf16x8 pa0 = ldfragE(sEw, w * 16 + lo16, quad);
        bf16x8 pa1 = ldfragE(sEw, w * 16 + lo16, quad + 4);
#pragma unroll
        for (int dt = 0; dt < 4; ++dt) {
            int dr = dt * 16 + lo16;
            bf16x8 vr0 = *(const bf16x8*)&gVr[(size_t)dr * 1024 + m0 + quad * 8];
            bf16x8 vr1 = *(const bf16x8*)&gVr[(size_t)dr * 1024 + m0 + 32 + quad * 8];
            bf16x8 vi0 = *(const bf16x8*)&gVi[(size_t)dr * 1024 + m0 + quad * 8];
            bf16x8 vi1 = *(const bf16x8*)&gVi[(size_t)dr * 1024 + m0 + 32 + quad * 8];
            aOutR[dt] = MFMA(pa0, vr0, aOutR[dt]);
            aOutR[dt] = MFMA(pa1, vr1, aOutR[dt]);
            aOutI[dt] = MFMA(pa0, vi0, aOutI[dt]);
            aOutI[dt] = MFMA(pa1, vi1, aOutI[dt]);
        }
    }

    // ---- epilogue ----
    const float* eCr = ws + WS_ECR;
    const float* eCi = ws + WS_ECI;
    const float* SVp = ws + WS_SVP;
    const size_t ooff = (size_t)BH_ * L_ * D_;

    float cden[4];
#pragma unroll
    for (int reg = 0; reg < 4; ++reg) {
        int r = w * 16 + quad * 4 + reg;
        cden[reg] = sDen[0][r] + sDen[1][r] + sDen[2][r] + sDen[3][r];
    }
#pragma unroll
    for (int dt = 0; dt < 4; ++dt) {
        int d = dt * 16 + lo16;
        float svr = 0.0f, svi = 0.0f;
#pragma unroll
        for (int c = 0; c < 4; ++c) {
            svr += SVp[0 * 8192 + bh * 256 + c * 64 + d];
            svi += SVp[1 * 8192 + bh * 256 + c * 64 + d];
        }
        float sp, cp;
        __sincosf((2.0f * PI_F / 64.0f) * (float)d, &sp, &cp);
#pragma unroll
        for (int reg = 0; reg < 4; ++reg) {
            int lrow = l0 + w * 16 + quad * 4 + reg;
            float numR = fmaf(cden[reg], svr, aOutR[dt][reg]) * 0.5f;
            float numI = fmaf(cden[reg], svi, aOutI[dt][reg]) * 0.5f;
            float Cr = eCr[lrow], Ci = eCi[lrow];
            float epr = cp * Cr - sp * Ci;
            float epi = sp * Cr + cp * Ci;
            size_t o = base + (size_t)lrow * 64 + d;
            out[o] = numR * epr - numI * epi;
            out[o + ooff] = numR * epi + numI * epr;
        }
    }
}

extern "C" void kernel_launch(void* const* d_in, const int* in_sizes, int n_in,
                              void* d_out, int out_size, void* d_ws, size_t ws_size,
                              hipStream_t stream) {
    const float* Qr = (const float*)d_in[0];
    const float* Qi = (const float*)d_in[1];
    const float* Kr = (const float*)d_in[2];
    const float* Ki = (const float*)d_in[3];
    const float* Vr = (const float*)d_in[4];
    const float* Vi = (const float*)d_in[5];
    float* ws = (float*)d_ws;
    float* out = (float*)d_out;

    // norms over LMAX in closed form (double): sum_{j=0}^{N-1} cos(a j)
    //   = cos(a(N-1)/2) sin(aN/2) / sin(a/2)
    const double fr[4] = {1.0, 0.5, 0.25, 0.1};
    float inv[4];
    for (int s = 0; s < 4; ++s) {
        double a = 2.0 * 3.14159265358979323846 * fr[s] / (double)(LMAX_ - 1);
        double S = 3.0 * LMAX_;
        const double mul[3] = {1.0, 0.5, 1.5};
        for (int k = 0; k < 3; ++k) {
            double x = a * mul[k];
            S += 2.0 * (cos(x * 1023.5) * sin(x * 1024.0) / sin(x * 0.5));
        }
        inv[s] = (float)(1.0 / sqrt(S));
    }
    float4 invn = make_float4(inv[0], inv[1], inv[2], inv[3]);

    prep_kernel<<<1568, BDIM, 0, stream>>>(Kr, Ki, Vr, Vi, ws, invn);
    attn3_kernel<<<BH_ * 16, BDIM, 0, stream>>>(Qr, Qi, ws, out);
}

// Round 5
// 198.757 us; speedup vs baseline: 1.5583x; 1.5583x over previous
//
#include <hip/hip_runtime.h>
#include <math.h>

typedef short bf16x8 __attribute__((ext_vector_type(8)));
typedef float f32x4 __attribute__((ext_vector_type(4)));

#define BDIM 256
constexpr int B_ = 2, H_ = 16, L_ = 1024, D_ = 64, LMAX_ = 2048;
constexpr int BH_ = B_ * H_;
constexpr float PI_F = 3.14159265358979323846f;

__device__ __forceinline__ unsigned short f2b(float x) {
    union { float f; unsigned u; } v; v.f = x;
    return (unsigned short)((v.u + 0x8000u) >> 16);  // round-half-up bf16
}
__device__ __forceinline__ unsigned pk2(float a, float b) {
    union { float f; unsigned u; } va, vb; va.f = a; vb.f = b;
    return ((va.u + 0x8000u) >> 16) | ((vb.u + 0x8000u) & 0xFFFF0000u);
}
__device__ __forceinline__ float b2f(unsigned short u) {
    union { unsigned u; float f; } v; v.u = ((unsigned)u) << 16;
    return v.f;
}
__device__ __forceinline__ uint4 pack4(const float4& a, const float4& b) {
    return make_uint4(pk2(a.x, a.y), pk2(a.z, a.w), pk2(b.x, b.y), pk2(b.z, b.w));
}

#define MFMA(a, b, c) __builtin_amdgcn_mfma_f32_16x16x32_bf16((a), (b), (c), 0, 0, 0)

// a_s(l) = sqrt(3 + 2cos t + 2cos t/2 + 2cos 3t/2) * invnorm_s,  t = 2*pi*f_s*l/(LMAX-1)
__device__ __forceinline__ float a_val(int s, int l, float4 invn) {
    const float fr = (s == 0) ? 1.0f : (s == 1) ? 0.5f : (s == 2) ? 0.25f : 0.1f;
    const float iv = (s == 0) ? invn.x : (s == 1) ? invn.y : (s == 2) ? invn.z : invn.w;
    float t = (2.0f * PI_F * fr / (float)(LMAX_ - 1)) * (float)l;
    float m2 = 3.0f + 2.0f * cosf(t) + 2.0f * cosf(0.5f * t) + 2.0f * cosf(1.5f * t);
    return sqrtf(fmaxf(m2, 0.0f)) * iv;
}

// swizzled K-tile fragment read: slot = row*8 + (g ^ (row&7)), 16B per slot
__device__ __forceinline__ bf16x8 frK(const unsigned short* sK, int row, int g) {
    return *(const bf16x8*)&sK[(row * 8 + (g ^ (row & 7))) * 8];
}
// swizzled V^T fragment read: [d][m-granule]
__device__ __forceinline__ bf16x8 frV(const unsigned short* sVt, int d, int g) {
    return *(const bf16x8*)&sVt[d * 64 + ((g ^ (d & 7)) << 3)];
}
// sE fragment read (row l, m-granule g), row stride 72
__device__ __forceinline__ bf16x8 ldfragE(const unsigned short* b, int row, int g) {
    return *(const bf16x8*)&b[row * 72 + ((g ^ (row & 7)) << 3)];
}

__launch_bounds__(BDIM, 2)
__global__ void attn_fused_kernel(const float* __restrict__ Qr, const float* __restrict__ Qi,
                                  const float* __restrict__ Kr, const float* __restrict__ Ki,
                                  const float* __restrict__ Vr, const float* __restrict__ Vi,
                                  float* __restrict__ out, float4 invn) {
    __shared__ unsigned short sK0[512 * 8], sK1[512 * 8];   // K tiles (swizzled slots)
    __shared__ unsigned short sVt0[64 * 64], sVt1[64 * 64]; // V^T tiles (swizzled)
    __shared__ unsigned short sE[64 * 72];                  // per-wave score slabs
    __shared__ unsigned short sAmb[4 * 1032];               // a/8 bf16 [s][l], padded
    __shared__ float sDen[4][64];
    __shared__ float sSV[2][4][64];                         // SumV partials [comp][wave][d]

    const int tid = threadIdx.x;
    const int lane = tid & 63;
    const int w = tid >> 6;
    const int lo16 = lane & 15;
    const int quad = lane >> 4;
    const int blk = blockIdx.x;
    const int bh = (blk & 7) * 4 + (blk >> 7);   // XCD-clustered
    const int qt = (blk >> 3) & 15;
    const int l0 = qt * 64;
    const size_t base = (size_t)bh * (L_ * D_);

    // ---- init: amb table in LDS ----
    for (int e = tid; e < 4096; e += BDIM) {
        int s = e >> 10, l = e & 1023;
        sAmb[s * 1032 + l] = f2b(a_val(s, l, invn) * 0.125f);
    }

    // ---- Q fragments from global fp32 (once) ----
    const int ql = l0 + w * 16 + lo16;
    bf16x8 fQr0, fQr1, fQi0, fQi1, fnQi0, fnQi1;
    {
        const float* qr = Qr + base + (size_t)ql * 64;
        const float* qi = Qi + base + (size_t)ql * 64;
        float4 a0 = *(const float4*)(qr + quad * 8);
        float4 a1 = *(const float4*)(qr + quad * 8 + 4);
        float4 b0 = *(const float4*)(qr + 32 + quad * 8);
        float4 b1 = *(const float4*)(qr + 32 + quad * 8 + 4);
        *(uint4*)&fQr0 = pack4(a0, a1);
        *(uint4*)&fQr1 = pack4(b0, b1);
        a0 = *(const float4*)(qi + quad * 8);
        a1 = *(const float4*)(qi + quad * 8 + 4);
        b0 = *(const float4*)(qi + 32 + quad * 8);
        b1 = *(const float4*)(qi + 32 + quad * 8 + 4);
        *(uint4*)&fQi0 = pack4(a0, a1);
        *(uint4*)&fQi1 = pack4(b0, b1);
        uint4 t0 = *(uint4*)&fQi0, t1 = *(uint4*)&fQi1;
        t0.x ^= 0x80008000u; t0.y ^= 0x80008000u; t0.z ^= 0x80008000u; t0.w ^= 0x80008000u;
        t1.x ^= 0x80008000u; t1.y ^= 0x80008000u; t1.z ^= 0x80008000u; t1.w ^= 0x80008000u;
        *(uint4*)&fnQi0 = t0; *(uint4*)&fnQi1 = t1;
    }

    // identity B-fragments for the MFMA transpose
    bf16x8 iLo, iHi;
#pragma unroll
    for (int j = 0; j < 8; ++j) {
        iLo[j] = (quad == (lo16 >> 3) && j == (lo16 & 7)) ? (short)0x3F80 : (short)0;
        iHi[j] = (quad == 2 + (lo16 >> 3) && j == (lo16 & 7)) ? (short)0x3F80 : (short)0;
    }

    // prefetch registers
    float4 pK[2][2][2];  // [comp][half(row 0-31 / 32-63)][float4]
    float4 pV[2][2][2];  // [comp][k-frag][float4]
    const int r0 = tid >> 3;
    const int gco = (tid & 7) ^ (r0 & 7);  // content granule for this thread's slots

#define PREF_K(m0n)                                                                     \
    {                                                                                   \
        _Pragma("unroll") for (int c = 0; c < 2; ++c) {                                 \
            const float* kp = (c ? Ki : Kr) + base;                                     \
            _Pragma("unroll") for (int h = 0; h < 2; ++h) {                             \
                const float* s = kp + (size_t)((m0n) + h * 32 + r0) * 64 + gco * 8;     \
                pK[c][h][0] = *(const float4*)s;                                        \
                pK[c][h][1] = *(const float4*)(s + 4);                                  \
            }                                                                           \
        }                                                                               \
    }
#define PREF_V(m0n)                                                                     \
    {                                                                                   \
        _Pragma("unroll") for (int c = 0; c < 2; ++c) {                                 \
            const float* vp = (c ? Vi : Vr) + base;                                     \
            _Pragma("unroll") for (int f = 0; f < 2; ++f) {                             \
                const float* s = vp + (size_t)((m0n) + w * 16 + lo16) * 64 + f * 32 + quad * 8; \
                pV[c][f][0] = *(const float4*)s;                                        \
                pV[c][f][1] = *(const float4*)(s + 4);                                  \
            }                                                                           \
        }                                                                               \
    }
#define WRITE_K()                                                                       \
    {                                                                                   \
        *(uint4*)&sK0[tid * 8] = pack4(pK[0][0][0], pK[0][0][1]);                       \
        *(uint4*)&sK0[(tid + 256) * 8] = pack4(pK[0][1][0], pK[0][1][1]);               \
        *(uint4*)&sK1[tid * 8] = pack4(pK[1][0][0], pK[1][0][1]);                       \
        *(uint4*)&sK1[(tid + 256) * 8] = pack4(pK[1][1][0], pK[1][1][1]);               \
    }

    // ================= sweep 0: denominators =================
    PREF_K(0);
    f32x4 accM1 = (f32x4){0.f, 0.f, 0.f, 0.f};
#pragma unroll 1
    for (int mt = 0; mt < 16; ++mt) {
        const int m0 = mt * 64;
        __syncthreads();
        WRITE_K();
        __syncthreads();
        if (mt < 15) PREF_K(m0 + 64);
#pragma unroll
        for (int ct = 0; ct < 4; ++ct) {
            const int mrow = ct * 16 + lo16;
            bf16x8 kr0 = frK(sK0, mrow, quad), kr1 = frK(sK0, mrow, quad + 4);
            bf16x8 ki0 = frK(sK1, mrow, quad), ki1 = frK(sK1, mrow, quad + 4);
            f32x4 aR = (f32x4){0.f, 0.f, 0.f, 0.f};
            f32x4 aI = (f32x4){0.f, 0.f, 0.f, 0.f};
            aR = MFMA(kr0, fQr0, aR);  aR = MFMA(kr1, fQr1, aR);
            aR = MFMA(ki0, fnQi0, aR); aR = MFMA(ki1, fnQi1, aR);
            aI = MFMA(ki0, fQr0, aI);  aI = MFMA(ki1, fQr1, aI);
            aI = MFMA(kr0, fQi0, aI);  aI = MFMA(kr1, fQi1, aI);
            float m0v = sqrtf(fmaf(aR[0], aR[0], aI[0] * aI[0]));
            float m1v = sqrtf(fmaf(aR[1], aR[1], aI[1] * aI[1]));
            float m2v = sqrtf(fmaf(aR[2], aR[2], aI[2] * aI[2]));
            float m3v = sqrtf(fmaf(aR[3], aR[3], aI[3] * aI[3]));
            int l = w * 16 + lo16;
            int gph = (ct * 2 + (quad >> 1)) ^ (l & 7);
            *(uint2*)&sE[l * 72 + gph * 8 + (quad & 1) * 4] =
                make_uint2(pk2(m0v, m1v), pk2(m2v, m3v));
        }
        // M1 += mag @ amb  (same-wave sE; amb rows 4-15 are implicit zeros)
        bf16x8 mf0 = ldfragE(sE, w * 16 + lo16, quad);
        bf16x8 mf1 = ldfragE(sE, w * 16 + lo16, quad + 4);
        bf16x8 b0 = (bf16x8){0, 0, 0, 0, 0, 0, 0, 0};
        bf16x8 b1 = (bf16x8){0, 0, 0, 0, 0, 0, 0, 0};
        if (lo16 < 4) {
            b0 = *(const bf16x8*)&sAmb[lo16 * 1032 + m0 + quad * 8];
            b1 = *(const bf16x8*)&sAmb[lo16 * 1032 + m0 + 32 + quad * 8];
        }
        accM1 = MFMA(mf0, b0, accM1);
        accM1 = MFMA(mf1, b1, accM1);
    }

    // denominators: den_s[l] = 1024 + a_s[l]*M1[l,s]
    if (lo16 < 4) {
#pragma unroll
        for (int reg = 0; reg < 4; ++reg) {
            int r = w * 16 + quad * 4 + reg;
            float alv = a_val(lo16, l0 + r, invn);
            sDen[lo16][r] = 1.0f / (1024.0f + alv * accM1[reg]);
        }
    }
    // prefetch sweep-1 tile 0 while the cosf-heavy uf build runs
    PREF_K(0);
    PREF_V(0);
    bf16x8 uf1 = (bf16x8){0, 0, 0, 0, 0, 0, 0, 0};
    bf16x8 uf2 = (bf16x8){0, 0, 0, 0, 0, 0, 0, 0};
    {
        float invq = sDen[quad][w * 16 + lo16];  // same-wave LDS
        float alq = a_val(quad, l0 + w * 16 + lo16, invn);
        uf1[0] = (short)f2b(invq * alq);
        uf2[0] = (short)f2b(0.5f * invq * alq * alq);
    }

    // ================= sweep 1: P' + PV =================
    f32x4 aOutR[4], aOutI[4];
#pragma unroll
    for (int dt = 0; dt < 4; ++dt) {
        aOutR[dt] = (f32x4){0.f, 0.f, 0.f, 0.f};
        aOutI[dt] = (f32x4){0.f, 0.f, 0.f, 0.f};
    }
    float sv[8];
#pragma unroll
    for (int i = 0; i < 8; ++i) sv[i] = 0.0f;

#pragma unroll 1
    for (int mt = 0; mt < 16; ++mt) {
        const int m0 = mt * 64;
        __syncthreads();
        WRITE_K();
        // V transpose via identity-MFMA: D regs = V^T (lane=d, regs=m-run)
#pragma unroll
        for (int c = 0; c < 2; ++c) {
            unsigned short* dst = c ? sVt1 : sVt0;
#pragma unroll
            for (int f = 0; f < 2; ++f) {
                bf16x8 af;
                *(uint4*)&af = pack4(pV[c][f][0], pV[c][f][1]);
                f32x4 z = (f32x4){0.f, 0.f, 0.f, 0.f};
                f32x4 dLo = MFMA(af, iLo, z);
                f32x4 dHi = MFMA(af, iHi, z);
                int gm = w * 2 + (quad >> 1);
                int dd = f * 32 + lo16;
                *(uint2*)&dst[dd * 64 + ((gm ^ (dd & 7)) << 3) + (quad & 1) * 4] =
                    make_uint2(pk2(dLo[0], dLo[1]), pk2(dLo[2], dLo[3]));
                sv[c * 4 + f * 2 + 0] += dLo[0] + dLo[1] + dLo[2] + dLo[3];
                dd = f * 32 + 16 + lo16;
                *(uint2*)&dst[dd * 64 + ((gm ^ (dd & 7)) << 3) + (quad & 1) * 4] =
                    make_uint2(pk2(dHi[0], dHi[1]), pk2(dHi[2], dHi[3]));
                sv[c * 4 + f * 2 + 1] += dHi[0] + dHi[1] + dHi[2] + dHi[3];
            }
        }
        __syncthreads();
        if (mt < 15) { PREF_K(m0 + 64); PREF_V(m0 + 64); }
#pragma unroll
        for (int ct = 0; ct < 4; ++ct) {
            const int mrow = ct * 16 + lo16;
            bf16x8 kr0 = frK(sK0, mrow, quad), kr1 = frK(sK0, mrow, quad + 4);
            bf16x8 ki0 = frK(sK1, mrow, quad), ki1 = frK(sK1, mrow, quad + 4);
            f32x4 aR = (f32x4){0.f, 0.f, 0.f, 0.f};
            f32x4 aI = (f32x4){0.f, 0.f, 0.f, 0.f};
            aR = MFMA(kr0, fQr0, aR);  aR = MFMA(kr1, fQr1, aR);
            aR = MFMA(ki0, fnQi0, aR); aR = MFMA(ki1, fnQi1, aR);
            aI = MFMA(ki0, fQr0, aI);  aI = MFMA(ki1, fQr1, aI);
            aI = MFMA(kr0, fQi0, aI);  aI = MFMA(kr1, fQi1, aI);
            // rank-4 A1/A2 (am2 = amb^2 on the fly)
            unsigned short amu = sAmb[quad * 1032 + m0 + ct * 16 + lo16];
            float amf = b2f(amu);
            bf16x8 bf1 = (bf16x8){0, 0, 0, 0, 0, 0, 0, 0};
            bf16x8 bf2 = (bf16x8){0, 0, 0, 0, 0, 0, 0, 0};
            bf1[0] = (short)amu;
            bf2[0] = (short)f2b(amf * amf);
            f32x4 z = (f32x4){0.f, 0.f, 0.f, 0.f};
            f32x4 a1 = MFMA(bf1, uf1, z);
            f32x4 a2 = MFMA(bf2, uf2, z);
            float p0, p1, p2, p3;
            {
                float msq = fmaf(aR[0], aR[0], aI[0] * aI[0]);
                p0 = fmaf(sqrtf(msq), a1[0], msq * a2[0]);
                msq = fmaf(aR[1], aR[1], aI[1] * aI[1]);
                p1 = fmaf(sqrtf(msq), a1[1], msq * a2[1]);
                msq = fmaf(aR[2], aR[2], aI[2] * aI[2]);
                p2 = fmaf(sqrtf(msq), a1[2], msq * a2[2]);
                msq = fmaf(aR[3], aR[3], aI[3] * aI[3]);
                p3 = fmaf(sqrtf(msq), a1[3], msq * a2[3]);
            }
            int l = w * 16 + lo16;
            int gph = (ct * 2 + (quad >> 1)) ^ (l & 7);
            *(uint2*)&sE[l * 72 + gph * 8 + (quad & 1) * 4] =
                make_uint2(pk2(p0, p1), pk2(p2, p3));
        }
        // PV: out += P' @ V
        bf16x8 pa0 = ldfragE(sE, w * 16 + lo16, quad);
        bf16x8 pa1 = ldfragE(sE, w * 16 + lo16, quad + 4);
#pragma unroll
        for (int dt = 0; dt < 4; ++dt) {
            int dr = dt * 16 + lo16;
            bf16x8 vr0 = frV(sVt0, dr, quad), vr1 = frV(sVt0, dr, quad + 4);
            bf16x8 vi0 = frV(sVt1, dr, quad), vi1 = frV(sVt1, dr, quad + 4);
            aOutR[dt] = MFMA(pa0, vr0, aOutR[dt]);
            aOutR[dt] = MFMA(pa1, vr1, aOutR[dt]);
            aOutI[dt] = MFMA(pa0, vi0, aOutI[dt]);
            aOutI[dt] = MFMA(pa1, vi1, aOutI[dt]);
        }
    }

    // ---- SumV reduction (quad butterfly + cross-wave via LDS) ----
#pragma unroll
    for (int t = 0; t < 8; ++t) {
        float v = sv[t];
        v += __shfl_xor(v, 16);
        v += __shfl_xor(v, 32);
        sv[t] = v;
    }
    if (quad == 0) {
#pragma unroll
        for (int t = 0; t < 8; ++t)
            sSV[t >> 2][w][(t & 3) * 16 + lo16] = sv[t];
    }
    __syncthreads();

    // ---- epilogue ----
    const size_t ooff = (size_t)BH_ * L_ * D_;
    float cden[4];
#pragma unroll
    for (int reg = 0; reg < 4; ++reg) {
        int r = w * 16 + quad * 4 + reg;
        cden[reg] = sDen[0][r] + sDen[1][r] + sDen[2][r] + sDen[3][r];
    }
    // expert eC per output row (10-term frequency comb, rotation recurrence)
    const float cE = rsqrtf(2048.0f) * rsqrtf(24.0f);
    float eRr[4], eRi[4];
#pragma unroll
    for (int reg = 0; reg < 4; ++reg) {
        int lrow = l0 + w * 16 + quad * 4 + reg;
        float tl = (2.0f * PI_F / (float)(LMAX_ - 1)) * (float)lrow;
        float s1, c1;
        __sincosf(0.1f * tl, &s1, &c1);
        const float W[10] = {1.f, 2.f, 3.f, 3.f, 3.f, 3.f, 3.f, 3.f, 2.f, 1.f};
        float cr = c1, ci = s1;
        float er = W[0] * cr, ei = W[0] * ci;
#pragma unroll
        for (int k = 1; k < 10; ++k) {
            float nr = cr * c1 - ci * s1;
            float ni = cr * s1 + ci * c1;
            cr = nr; ci = ni;
            er = fmaf(W[k], cr, er);
            ei = fmaf(W[k], ci, ei);
        }
        eRr[reg] = er * cE;
        eRi[reg] = ei * cE;
    }
#pragma unroll
    for (int dt = 0; dt < 4; ++dt) {
        int d = dt * 16 + lo16;
        float svr = sSV[0][0][d] + sSV[0][1][d] + sSV[0][2][d] + sSV[0][3][d];
        float svi = sSV[1][0][d] + sSV[1][1][d] + sSV[1][2][d] + sSV[1][3][d];
        float sp, cp;
        __sincosf((2.0f * PI_F / 64.0f) * (float)d, &sp, &cp);
#pragma unroll
        for (int reg = 0; reg < 4; ++reg) {
            int lrow = l0 + w * 16 + quad * 4 + reg;
            float numR = fmaf(cden[reg], svr, aOutR[dt][reg]) * 0.5f;
            float numI = fmaf(cden[reg], svi, aOutI[dt][reg]) * 0.5f;
            float epr = cp * eRr[reg] - sp * eRi[reg];
            float epi = sp * eRr[reg] + cp * eRi[reg];
            size_t o = base + (size_t)lrow * 64 + d;
            out[o] = numR * epr - numI * epi;
            out[o + ooff] = numR * epi + numI * epr;
        }
    }
#undef PREF_K
#undef PREF_V
#undef WRITE_K
}

extern "C" void kernel_launch(void* const* d_in, const int* in_sizes, int n_in,
                              void* d_out, int out_size, void* d_ws, size_t ws_size,
                              hipStream_t stream) {
    const float* Qr = (const float*)d_in[0];
    const float* Qi = (const float*)d_in[1];
    const float* Kr = (const float*)d_in[2];
    const float* Ki = (const float*)d_in[3];
    const float* Vr = (const float*)d_in[4];
    const float* Vi = (const float*)d_in[5];
    float* out = (float*)d_out;

    // pattern norms over LMAX in closed form (double)
    const double fr[4] = {1.0, 0.5, 0.25, 0.1};
    float inv[4];
    for (int s = 0; s < 4; ++s) {
        double a = 2.0 * 3.14159265358979323846 * fr[s] / (double)(LMAX_ - 1);
        double S = 3.0 * LMAX_;
        const double mul[3] = {1.0, 0.5, 1.5};
        for (int k = 0; k < 3; ++k) {
            double x = a * mul[k];
            S += 2.0 * (cos(x * 1023.5) * sin(x * 1024.0) / sin(x * 0.5));
        }
        inv[s] = (float)(1.0 / sqrt(S));
    }
    float4 invn = make_float4(inv[0], inv[1], inv[2], inv[3]);

    attn_fused_kernel<<<512, BDIM, 0, stream>>>(Qr, Qi, Kr, Ki, Vr, Vi, out, invn);
}

// Round 7
// 160.637 us; speedup vs baseline: 1.9280x; 1.2373x over previous
//
#include <hip/hip_runtime.h>
#include <math.h>

typedef short bf16x8 __attribute__((ext_vector_type(8)));
typedef float f32x4 __attribute__((ext_vector_type(4)));

#define BDIM 256
constexpr int B_ = 2, H_ = 16, L_ = 1024, D_ = 64, LMAX_ = 2048;
constexpr int BH_ = B_ * H_;
constexpr float PI_F = 3.14159265358979323846f;

// ws float offsets
constexpr int WS_SVP = 0;                    // fp32 [2][32][16][64] SumV partials
constexpr int WS_KBR = 65536;                // u16 [32][1024][64]
constexpr int WS_KBI = WS_KBR + 1048576;
constexpr int WS_VTR = WS_KBI + 1048576;     // u16 [32][64][1024]
constexpr int WS_VTI = WS_VTR + 1048576;

__device__ __forceinline__ unsigned short f2b(float x) {
    union { float f; unsigned u; } v; v.f = x;
    return (unsigned short)((v.u + 0x8000u) >> 16);
}
__device__ __forceinline__ unsigned pk2(float a, float b) {
    union { float f; unsigned u; } va, vb; va.f = a; vb.f = b;
    return ((va.u + 0x8000u) >> 16) | ((vb.u + 0x8000u) & 0xFFFF0000u);
}
__device__ __forceinline__ uint4 pack4(const float4& a, const float4& b) {
    return make_uint4(pk2(a.x, a.y), pk2(a.z, a.w), pk2(b.x, b.y), pk2(b.z, b.w));
}

#define MFMA(a, b, c) __builtin_amdgcn_mfma_f32_16x16x32_bf16((a), (b), (c), 0, 0, 0)

__device__ __forceinline__ float a_val(int s, int l, float4 invn) {
    const float fr = (s == 0) ? 1.0f : (s == 1) ? 0.5f : (s == 2) ? 0.25f : 0.1f;
    const float iv = (s == 0) ? invn.x : (s == 1) ? invn.y : (s == 2) ? invn.z : invn.w;
    float t = (2.0f * PI_F * fr / (float)(LMAX_ - 1)) * (float)l;
    float m2 = 3.0f + 2.0f * cosf(t) + 2.0f * cosf(0.5f * t) + 2.0f * cosf(1.5f * t);
    return sqrtf(fmaxf(m2, 0.0f)) * iv;
}

// ---------------- prep: K->bf16, V->V^T bf16, SumV partials ----------------
// 1280 blocks: [0,256) K conv; [256,1280) V^T + SVp per (bh,mt,comp) tile.
__global__ __launch_bounds__(BDIM)
void prep_kernel(const float* __restrict__ Kr, const float* __restrict__ Ki,
                 const float* __restrict__ Vr, const float* __restrict__ Vi,
                 float* __restrict__ ws) {
    const int tid = threadIdx.x;
    const int blk = blockIdx.x;
    unsigned short* KbR = (unsigned short*)(ws + WS_KBR);
    unsigned short* KbI = (unsigned short*)(ws + WS_KBI);
    unsigned short* VtR = (unsigned short*)(ws + WS_VTR);
    unsigned short* VtI = (unsigned short*)(ws + WS_VTI);

    if (blk < 256) {
        // K -> bf16: 2M elems per comp / 128 blocks = 16384 per block
        const int comp = blk >> 7;
        const float* src = comp ? Ki : Kr;
        unsigned short* dst = comp ? KbI : KbR;
        size_t b0 = (size_t)(blk & 127) * 16384;
#pragma unroll
        for (int i = 0; i < 4; ++i) {
            size_t e = b0 + (size_t)(i * 256 + tid) * 16;
            float4 x0 = *(const float4*)(src + e);
            float4 x1 = *(const float4*)(src + e + 4);
            float4 x2 = *(const float4*)(src + e + 8);
            float4 x3 = *(const float4*)(src + e + 12);
            *(uint4*)(dst + e) = pack4(x0, x1);
            *(uint4*)(dst + e + 8) = pack4(x2, x3);
        }
    } else {
        // V^T tile + SVp: vb -> (comp, mt, bh)
        __shared__ unsigned short sT[64 * 68];
        __shared__ float sRed[4 * 64];
        const int vb = blk - 256;
        const int comp = vb & 1, mt = (vb >> 1) & 15, bh = vb >> 5;
        const int m0 = mt * 64;
        const float* src = (comp ? Vi : Vr) + (size_t)bh * 65536 + (size_t)m0 * 64;
        unsigned short* dstA = (comp ? VtI : VtR) + (size_t)bh * 65536;
        // stage tile bf16 into LDS
#pragma unroll
        for (int i = 0; i < 4; ++i) {
            int e = i * 256 + tid;
            int m = e >> 4, d4 = (e & 15) * 4;
            float4 x = *(const float4*)(src + (size_t)m * 64 + d4);
            *(uint2*)&sT[m * 68 + d4] = make_uint2(pk2(x.x, x.y), pk2(x.z, x.w));
        }
        // SVp: fp32 column sums over the 64 m of this tile
        {
            int d = tid & 63, grp = tid >> 6;
            float s = 0.0f;
#pragma unroll
            for (int k = 0; k < 16; ++k) s += src[(size_t)(grp * 16 + k) * 64 + d];
            sRed[grp * 64 + d] = s;
        }
        __syncthreads();
        // transposed write: thread -> d = tid>>2, ms = (tid&3)*16
        {
            int d = tid >> 2, ms = (tid & 3) * 16;
            unsigned short v[16];
#pragma unroll
            for (int k = 0; k < 16; ++k) v[k] = sT[(ms + k) * 68 + d];
            unsigned short* dst = dstA + (size_t)d * 1024 + m0 + ms;
            *(uint4*)dst = make_uint4((unsigned)v[0] | ((unsigned)v[1] << 16),
                                      (unsigned)v[2] | ((unsigned)v[3] << 16),
                                      (unsigned)v[4] | ((unsigned)v[5] << 16),
                                      (unsigned)v[6] | ((unsigned)v[7] << 16));
            *(uint4*)(dst + 8) = make_uint4((unsigned)v[8] | ((unsigned)v[9] << 16),
                                            (unsigned)v[10] | ((unsigned)v[11] << 16),
                                            (unsigned)v[12] | ((unsigned)v[13] << 16),
                                            (unsigned)v[14] | ((unsigned)v[15] << 16));
        }
        if (tid < 64)
            ws[WS_SVP + comp * 32768 + bh * 1024 + mt * 64 + tid] =
                sRed[tid] + sRed[64 + tid] + sRed[128 + tid] + sRed[192 + tid];
    }
}

// ---------------- attention: single sweep ----------------
__device__ __forceinline__ void stage64s(const unsigned short* g0, int stride,
                                         unsigned short* lds, int w, int lane) {
#pragma unroll
    for (int i = 0; i < 2; ++i) {
        int c = w * 2 + i;
        int lrow = c * 8 + (lane >> 3);
        int lg = (lane & 7) ^ (lrow & 7);
        const unsigned short* src = g0 + (size_t)lrow * stride + lg * 8;
        __builtin_amdgcn_global_load_lds(
            (const __attribute__((address_space(1))) void*)src,
            (__attribute__((address_space(3))) void*)(lds + c * 512), 16, 0, 0);
    }
}
__device__ __forceinline__ bf16x8 ldfrag(const unsigned short* b, int row, int g) {
    return *(const bf16x8*)&b[row * 64 + ((g ^ (row & 7)) << 3)];
}
__device__ __forceinline__ bf16x8 ldfragE(const unsigned short* b, int row, int g) {
    return *(const bf16x8*)&b[row * 72 + ((g ^ (row & 7)) << 3)];
}

__global__ __launch_bounds__(BDIM, 2)
void attn_kernel(const float* __restrict__ Qr, const float* __restrict__ Qi,
                 const float* __restrict__ ws, float* __restrict__ out, float4 invn) {
    __shared__ unsigned short sK0[4096], sK1[4096];
    __shared__ unsigned short sV0[4096], sV1[4096];
    __shared__ unsigned short sE[64 * 72];
    __shared__ unsigned short sMg[64 * 72];
    __shared__ unsigned short sAmb[4 * 1032];
    __shared__ float sDen[4 * 64];

    const int tid = threadIdx.x;
    const int lane = tid & 63;
    const int w = tid >> 6;
    const int lo16 = lane & 15;
    const int quad = lane >> 4;
    const int blk = blockIdx.x;
    const int bh = (blk & 7) * 4 + (blk >> 7);   // XCD-clustered
    const int qt = (blk >> 3) & 15;
    const int l0 = qt * 64;
    const size_t base = (size_t)bh * (L_ * D_);

    const unsigned short* gKr = (const unsigned short*)(ws + WS_KBR) + (size_t)bh * 65536;
    const unsigned short* gKi = (const unsigned short*)(ws + WS_KBI) + (size_t)bh * 65536;
    const unsigned short* gVr = (const unsigned short*)(ws + WS_VTR) + (size_t)bh * 65536;
    const unsigned short* gVi = (const unsigned short*)(ws + WS_VTI) + (size_t)bh * 65536;

    // amb table (a/8 bf16) in LDS
    for (int e = tid; e < 4096; e += BDIM) {
        int s = e >> 10, l = e & 1023;
        sAmb[s * 1032 + l] = f2b(a_val(s, l, invn) * 0.125f);
    }

    // Q fragments (register-resident)
    bf16x8 fQr0, fQr1, fQi0, fQi1, fnQi0, fnQi1;
    {
        const int ql = l0 + w * 16 + lo16;
        const float* qr = Qr + base + (size_t)ql * 64;
        const float* qi = Qi + base + (size_t)ql * 64;
        float4 a0 = *(const float4*)(qr + quad * 8);
        float4 a1 = *(const float4*)(qr + quad * 8 + 4);
        float4 b0 = *(const float4*)(qr + 32 + quad * 8);
        float4 b1 = *(const float4*)(qr + 32 + quad * 8 + 4);
        *(uint4*)&fQr0 = pack4(a0, a1);
        *(uint4*)&fQr1 = pack4(b0, b1);
        a0 = *(const float4*)(qi + quad * 8);
        a1 = *(const float4*)(qi + quad * 8 + 4);
        b0 = *(const float4*)(qi + 32 + quad * 8);
        b1 = *(const float4*)(qi + 32 + quad * 8 + 4);
        *(uint4*)&fQi0 = pack4(a0, a1);
        *(uint4*)&fQi1 = pack4(b0, b1);
        uint4 t0 = *(uint4*)&fQi0, t1 = *(uint4*)&fQi1;
        t0.x ^= 0x80008000u; t0.y ^= 0x80008000u; t0.z ^= 0x80008000u; t0.w ^= 0x80008000u;
        t1.x ^= 0x80008000u; t1.y ^= 0x80008000u; t1.z ^= 0x80008000u; t1.w ^= 0x80008000u;
        *(uint4*)&fnQi0 = t0; *(uint4*)&fnQi1 = t1;
    }

    // uf1a: scale s=quad, al_s[l]/1024 in k-slot 0 (rank-4 trick)
    bf16x8 uf1a = (bf16x8){0, 0, 0, 0, 0, 0, 0, 0};
    uf1a[0] = (short)f2b(a_val(quad, l0 + w * 16 + lo16, invn) * (1.0f / 1024.0f));

    f32x4 accM1 = (f32x4){0.f, 0.f, 0.f, 0.f};
    f32x4 aOutR[4], aOutI[4];
#pragma unroll
    for (int dt = 0; dt < 4; ++dt) {
        aOutR[dt] = (f32x4){0.f, 0.f, 0.f, 0.f};
        aOutI[dt] = (f32x4){0.f, 0.f, 0.f, 0.f};
    }

#pragma unroll 1
    for (int mt = 0; mt < 16; ++mt) {
        const int m0 = mt * 64;
        __syncthreads();
        stage64s(gKr + (size_t)m0 * 64, 64, sK0, w, lane);
        stage64s(gKi + (size_t)m0 * 64, 64, sK1, w, lane);
        stage64s(gVr + m0, 1024, sV0, w, lane);
        stage64s(gVi + m0, 1024, sV1, w, lane);
        __syncthreads();

#pragma unroll
        for (int ct = 0; ct < 4; ++ct) {
            const int mrow = ct * 16 + lo16;
            bf16x8 kr0 = ldfrag(sK0, mrow, quad), kr1 = ldfrag(sK0, mrow, quad + 4);
            bf16x8 ki0 = ldfrag(sK1, mrow, quad), ki1 = ldfrag(sK1, mrow, quad + 4);
            f32x4 aR = (f32x4){0.f, 0.f, 0.f, 0.f};
            f32x4 aI = (f32x4){0.f, 0.f, 0.f, 0.f};
            aR = MFMA(kr0, fQr0, aR);  aR = MFMA(kr1, fQr1, aR);   // S^T = K·Q^T
            aR = MFMA(ki0, fnQi0, aR); aR = MFMA(ki1, fnQi1, aR);
            aI = MFMA(ki0, fQr0, aI);  aI = MFMA(ki1, fQr1, aI);
            aI = MFMA(kr0, fQi0, aI);  aI = MFMA(kr1, fQi1, aI);
            float mg0 = sqrtf(fmaf(aR[0], aR[0], aI[0] * aI[0]));
            float mg1 = sqrtf(fmaf(aR[1], aR[1], aI[1] * aI[1]));
            float mg2 = sqrtf(fmaf(aR[2], aR[2], aI[2] * aI[2]));
            float mg3 = sqrtf(fmaf(aR[3], aR[3], aI[3] * aI[3]));
            // P'[l,m] = (sum_s al_s[l]·am_s[m]/1024) · mag, rank-4 MFMA
            bf16x8 bf1 = (bf16x8){0, 0, 0, 0, 0, 0, 0, 0};
            bf1[0] = (short)sAmb[quad * 1032 + m0 + ct * 16 + lo16];
            f32x4 z = (f32x4){0.f, 0.f, 0.f, 0.f};
            f32x4 a1 = MFMA(bf1, uf1a, z);
            float p0 = mg0 * a1[0], p1 = mg1 * a1[1];
            float p2 = mg2 * a1[2], p3 = mg3 * a1[3];
            int l = w * 16 + lo16;
            int gph = (ct * 2 + (quad >> 1)) ^ (l & 7);
            *(uint2*)&sE[l * 72 + gph * 8 + (quad & 1) * 4] =
                make_uint2(pk2(p0, p1), pk2(p2, p3));
            *(uint2*)&sMg[l * 72 + gph * 8 + (quad & 1) * 4] =
                make_uint2(pk2(mg0, mg1), pk2(mg2, mg3));
        }
        // M1 matvec for exact denominators (same-wave slab round-trip)
        {
            bf16x8 mf0 = ldfragE(sMg, w * 16 + lo16, quad);
            bf16x8 mf1 = ldfragE(sMg, w * 16 + lo16, quad + 4);
            bf16x8 b0 = (bf16x8){0, 0, 0, 0, 0, 0, 0, 0};
            bf16x8 b1 = (bf16x8){0, 0, 0, 0, 0, 0, 0, 0};
            if (lo16 < 4) {
                b0 = *(const bf16x8*)&sAmb[lo16 * 1032 + m0 + quad * 8];
                b1 = *(const bf16x8*)&sAmb[lo16 * 1032 + m0 + 32 + quad * 8];
            }
            accM1 = MFMA(mf0, b0, accM1);
            accM1 = MFMA(mf1, b1, accM1);
        }
        // PV: out += P' @ V
        {
            bf16x8 pa0 = ldfragE(sE, w * 16 + lo16, quad);
            bf16x8 pa1 = ldfragE(sE, w * 16 + lo16, quad + 4);
#pragma unroll
            for (int dt = 0; dt < 4; ++dt) {
                int dr = dt * 16 + lo16;
                bf16x8 vr0 = ldfrag(sV0, dr, quad), vr1 = ldfrag(sV0, dr, quad + 4);
                bf16x8 vi0 = ldfrag(sV1, dr, quad), vi1 = ldfrag(sV1, dr, quad + 4);
                aOutR[dt] = MFMA(pa0, vr0, aOutR[dt]);
                aOutR[dt] = MFMA(pa1, vr1, aOutR[dt]);
                aOutI[dt] = MFMA(pa0, vi0, aOutI[dt]);
                aOutI[dt] = MFMA(pa1, vi1, aOutI[dt]);
            }
        }
    }

    // exact denominators (epilogue-only): den_s[l] = 1024 + al_s[l]·M1[l,s]
    if (lo16 < 4) {
#pragma unroll
        for (int reg = 0; reg < 4; ++reg) {
            int r = w * 16 + quad * 4 + reg;
            float alv = a_val(lo16, l0 + r, invn);
            sDen[lo16 * 64 + r] = 1.0f / (1024.0f + alv * accM1[reg]);
        }
    }
    float cden[4];
#pragma unroll
    for (int reg = 0; reg < 4; ++reg) {
        int r = w * 16 + quad * 4 + reg;   // same-wave LDS read
        cden[reg] = sDen[r] + sDen[64 + r] + sDen[128 + r] + sDen[192 + r];
    }

    // expert eC per output row (10-term frequency comb)
    const float cE = rsqrtf(2048.0f) * rsqrtf(24.0f);
    float eRr[4], eRi[4];
#pragma unroll
    for (int reg = 0; reg < 4; ++reg) {
        int lrow = l0 + w * 16 + quad * 4 + reg;
        float tl = (2.0f * PI_F / (float)(LMAX_ - 1)) * (float)lrow;
        float s1, c1;
        __sincosf(0.1f * tl, &s1, &c1);
        const float W[10] = {1.f, 2.f, 3.f, 3.f, 3.f, 3.f, 3.f, 3.f, 2.f, 1.f};
        float cr = c1, ci = s1;
        float er = W[0] * cr, ei = W[0] * ci;
#pragma unroll
        for (int k = 1; k < 10; ++k) {
            float nr = cr * c1 - ci * s1;
            float ni = cr * s1 + ci * c1;
            cr = nr; ci = ni;
            er = fmaf(W[k], cr, er);
            ei = fmaf(W[k], ci, ei);
        }
        eRr[reg] = er * cE;
        eRi[reg] = ei * cE;
    }

    const size_t ooff = (size_t)BH_ * L_ * D_;
#pragma unroll
    for (int dt = 0; dt < 4; ++dt) {
        int d = dt * 16 + lo16;
        float svr = 0.0f, svi = 0.0f;
#pragma unroll
        for (int q = 0; q < 16; ++q) {
            svr += ws[WS_SVP + bh * 1024 + q * 64 + d];
            svi += ws[WS_SVP + 32768 + bh * 1024 + q * 64 + d];
        }
        float sp, cp;
        __sincosf((2.0f * PI_F / 64.0f) * (float)d, &sp, &cp);
#pragma unroll
        for (int reg = 0; reg < 4; ++reg) {
            int lrow = l0 + w * 16 + quad * 4 + reg;
            float numR = fmaf(cden[reg], svr, aOutR[dt][reg]) * 0.5f;
            float numI = fmaf(cden[reg], svi, aOutI[dt][reg]) * 0.5f;
            float epr = cp * eRr[reg] - sp * eRi[reg];
            float epi = sp * eRr[reg] + cp * eRi[reg];
            size_t o = base + (size_t)lrow * 64 + d;
            out[o] = numR * epr - numI * epi;
            out[o + ooff] = numR * epi + numI * epr;
        }
    }
}

extern "C" void kernel_launch(void* const* d_in, const int* in_sizes, int n_in,
                              void* d_out, int out_size, void* d_ws, size_t ws_size,
                              hipStream_t stream) {
    const float* Qr = (const float*)d_in[0];
    const float* Qi = (const float*)d_in[1];
    const float* Kr = (const float*)d_in[2];
    const float* Ki = (const float*)d_in[3];
    const float* Vr = (const float*)d_in[4];
    const float* Vi = (const float*)d_in[5];
    float* ws = (float*)d_ws;
    float* out = (float*)d_out;

    // pattern norms over LMAX in closed form (double)
    const double fr[4] = {1.0, 0.5, 0.25, 0.1};
    float inv[4];
    for (int s = 0; s < 4; ++s) {
        double a = 2.0 * 3.14159265358979323846 * fr[s] / (double)(LMAX_ - 1);
        double S = 3.0 * LMAX_;
        const double mul[3] = {1.0, 0.5, 1.5};
        for (int k = 0; k < 3; ++k) {
            double x = a * mul[k];
            S += 2.0 * (cos(x * 1023.5) * sin(x * 1024.0) / sin(x * 0.5));
        }
        inv[s] = (float)(1.0 / sqrt(S));
    }
    float4 invn = make_float4(inv[0], inv[1], inv[2], inv[3]);

    prep_kernel<<<1280, BDIM, 0, stream>>>(Kr, Ki, Vr, Vi, ws);
    attn_kernel<<<512, BDIM, 0, stream>>>(Qr, Qi, ws, out, invn);
}